// Round 2
// baseline (306.726 us; speedup 1.0000x reference)
//
#include <hip/hip_runtime.h>
#include <math.h>

// out[b,s,d] = emb_table[x[b,s], d] + pe[s,d]
//   pe[s, 2i]   = sin(s * f_i),  pe[s, 2i+1] = cos(s * f_i),  f_i = 10000^(-2i/1024)
// D_M = 1024, B = 8, S = 4096, VOCAB = 50257 (fp32 table)

#define D_M   1024
#define SEQ   4096
#define BATCH 8

__global__ __launch_bounds__(256) void SinusoidalEmbedding_83030307766274_kernel(
    const int* __restrict__ x,
    const float* __restrict__ emb_table,
    float* __restrict__ out)
{
    const int s  = blockIdx.x;     // sequence position, [0, SEQ)
    const int d4 = threadIdx.x;    // float4 column index, [0, 256)

    // ---- positional encoding, computed ONCE per (s, d4), reused for all 8 batch rows ----
    // inv_freq(i) = 10000^(-2i/D) = exp2(i * c),  c = -2*log2(10000)/D
    // Work in revolutions for hardware v_sin/v_cos: r = s * inv_freq / (2*pi)
    const float c      = -2.0f * 13.28771237954945f / (float)D_M;
    const float inv2pi = 0.15915494309189535f;
    const float i0 = (float)(2 * d4);
    const float f0 = exp2f(i0 * c) * inv2pi;          // turns per position, pair i0
    const float f1 = exp2f((i0 + 1.0f) * c) * inv2pi; // turns per position, pair i0+1
    const float sp = (float)s;

    // range-reduce to [0,1) turns, then hardware sin/cos (v_fract_f32 + v_sin/cos_f32)
    float r0 = __builtin_amdgcn_fractf(sp * f0);
    float r1 = __builtin_amdgcn_fractf(sp * f1);
    float pe_x = __builtin_amdgcn_sinf(r0);
    float pe_y = __builtin_amdgcn_cosf(r0);
    float pe_z = __builtin_amdgcn_sinf(r1);
    float pe_w = __builtin_amdgcn_cosf(r1);

    // ---- gather 8 rows (one per batch), 8 independent in-flight dwordx4 loads ----
    int rows[BATCH];
#pragma unroll
    for (int b = 0; b < BATCH; ++b)
        rows[b] = x[b * SEQ + s];          // block-uniform -> scalarized

    float4 v[BATCH];
#pragma unroll
    for (int b = 0; b < BATCH; ++b)
        v[b] = ((const float4*)(emb_table + (size_t)rows[b] * D_M))[d4];

    float4* __restrict__ o4 = (float4*)out;
#pragma unroll
    for (int b = 0; b < BATCH; ++b) {
        float4 o = v[b];
        o.x += pe_x;  // even col: sin
        o.y += pe_y;  // odd  col: cos
        o.z += pe_z;
        o.w += pe_w;
        o4[((size_t)b * SEQ + s) * (D_M / 4) + d4] = o;
    }
}

extern "C" void kernel_launch(void* const* d_in, const int* in_sizes, int n_in,
                              void* d_out, int out_size, void* d_ws, size_t ws_size,
                              hipStream_t stream)
{
    const int*   x         = (const int*)d_in[0];     // [B, S] token ids (int32)
    const float* emb_table = (const float*)d_in[1];   // [VOCAB, D_M] fp32
    float*       out       = (float*)d_out;           // [B, S, D_M] fp32

    SinusoidalEmbedding_83030307766274_kernel<<<SEQ, 256, 0, stream>>>(x, emb_table, out);
}